// Round 12
// baseline (154.047 us; speedup 1.0000x reference)
//
#include <hip/hip_runtime.h>
#include <hip/hip_fp16.h>

// ---------------------------------------------------------------------------
// Round-12: r10 pipeline with bsort fused into gather.
//   memset(counts) ; convhist (fp32->fp16 table conv + bucket minihist) ;
//   scan (1 tiny block: bucket offsets) ; bin (r10-proven: rank in LDS,
//   coalesced int2 flush into 64-node bucket runs) ; bgather (1 block/bucket:
//   LDS counting-sort of the bucket, esum at load time, then 8 waves x 8
//   node-slots of r10's 8-deep register gather, direct linear row writes).
// Key: gpay.x = (dst&63)<<17 | src  (needs N <= 2^17), gpay.y = efeat bits.
// ---------------------------------------------------------------------------

#define NB_SHIFT 6
#define BNODES   64           // nodes per bucket
#define SRC_BITS 17
#define SRC_MASK ((1 << SRC_BITS) - 1)
#define BIN_S    4096         // edges per bin/hist block
#define BIN_T    512
#define GAT_T    512          // bgather threads (8 waves)
#define SGCAP    2048         // bgather sort-chunk capacity
#define MAXNB    2048

// Fused: blocks [0, c_blocks) convert the table fp32->fp16; the rest
// histogram dst into NB bucket counts.
__global__ __launch_bounds__(BIN_T) void convhist_kernel(const float* __restrict__ g,
                                                         __half* __restrict__ h,
                                                         int n_emb, int c_blocks,
                                                         const int* __restrict__ dst,
                                                         int* __restrict__ counts,
                                                         int E, int NB) {
    __shared__ int cnt[MAXNB];
    int t = threadIdx.x;

    if (blockIdx.x < c_blocks) {
        int i = (blockIdx.x * BIN_T + t) * 8;
        if (i + 7 < n_emb) {
            float4 a = *(const float4*)(g + i);
            float4 b = *(const float4*)(g + i + 4);
            __half2 h0 = __floats2half2_rn(a.x, a.y);
            __half2 h1 = __floats2half2_rn(a.z, a.w);
            __half2 h2 = __floats2half2_rn(b.x, b.y);
            __half2 h3 = __floats2half2_rn(b.z, b.w);
            int4 o;
            o.x = *(int*)&h0; o.y = *(int*)&h1; o.z = *(int*)&h2; o.w = *(int*)&h3;
            *(int4*)(h + i) = o;
        } else {
            for (int k = i; k < n_emb; ++k) h[k] = __float2half(g[k]);
        }
        return;
    }

    int hb = blockIdx.x - c_blocks;
    for (int i = t; i < MAXNB; i += BIN_T) cnt[i] = 0;
    __syncthreads();
    int e0 = hb * BIN_S + t * 8;
    if (e0 + 7 < E) {
        int4 a = *(const int4*)(dst + e0);
        int4 b = *(const int4*)(dst + e0 + 4);
        atomicAdd(&cnt[a.x >> NB_SHIFT], 1);
        atomicAdd(&cnt[a.y >> NB_SHIFT], 1);
        atomicAdd(&cnt[a.z >> NB_SHIFT], 1);
        atomicAdd(&cnt[a.w >> NB_SHIFT], 1);
        atomicAdd(&cnt[b.x >> NB_SHIFT], 1);
        atomicAdd(&cnt[b.y >> NB_SHIFT], 1);
        atomicAdd(&cnt[b.z >> NB_SHIFT], 1);
        atomicAdd(&cnt[b.w >> NB_SHIFT], 1);
    } else {
        for (int k = e0; k < E; ++k) atomicAdd(&cnt[dst[k] >> NB_SHIFT], 1);
    }
    __syncthreads();
    for (int i = t; i < NB; i += BIN_T)
        if (cnt[i]) atomicAdd(&counts[i], cnt[i]);
}

// Exclusive scan over NB (<=2048) counters; one block, 1024 threads, 2/thread.
__global__ void scan_kernel(const int* __restrict__ counts,
                            int* __restrict__ goff, int* __restrict__ gcur,
                            int NB) {
    __shared__ int sh[1024];
    int t = threadIdx.x;
    int c0 = (2 * t     < NB) ? counts[2 * t]     : 0;
    int c1 = (2 * t + 1 < NB) ? counts[2 * t + 1] : 0;
    int s  = c0 + c1;
    sh[t] = s;
    __syncthreads();
    for (int o = 1; o < 1024; o <<= 1) {
        int u = (t >= o) ? sh[t - o] : 0;
        __syncthreads();
        sh[t] += u;
        __syncthreads();
    }
    int ex = sh[t] - s;
    if (2 * t < NB)     { goff[2 * t]     = ex;      gcur[2 * t]     = ex;      }
    if (2 * t + 1 < NB) { goff[2 * t + 1] = ex + c0; gcur[2 * t + 1] = ex + c0; }
    if (t == 1023) goff[NB] = sh[1023];
}

// r10-proven bin: local histogram+rank, shfl scans, stage int2, coalesced flush.
__global__ __launch_bounds__(BIN_T) void bin_kernel(const int* __restrict__ src,
                                                    const float* __restrict__ ef,
                                                    const int* __restrict__ dst,
                                                    int* __restrict__ gcur,
                                                    int2* __restrict__ gpay, int E) {
    __shared__ int cnt[MAXNB];              // 8 KB
    __shared__ int lbase[MAXNB];            // 8 KB
    __shared__ int wsum[8];
    __shared__ int wbase[8];
    __shared__ int2 stage[BIN_S];           // 32 KB
    __shared__ unsigned short sbuck[BIN_S]; // 8 KB

    const int t    = threadIdx.x;
    const int lane = t & 63;
    const int wv   = t >> 6;

    for (int i = t; i < MAXNB; i += BIN_T) cnt[i] = 0;
    __syncthreads();

    int e0 = blockIdx.x * BIN_S + t * 8;
    int dv[8], sv[8], bk[8], rk[8];
    float ev[8];

    if (e0 + 7 < E) {
        *(int4*)&dv[0]   = *(const int4*)(dst + e0);
        *(int4*)&dv[4]   = *(const int4*)(dst + e0 + 4);
        *(int4*)&sv[0]   = *(const int4*)(src + e0);
        *(int4*)&sv[4]   = *(const int4*)(src + e0 + 4);
        *(float4*)&ev[0] = *(const float4*)(ef + e0);
        *(float4*)&ev[4] = *(const float4*)(ef + e0 + 4);
#pragma unroll
        for (int k = 0; k < 8; ++k) {
            bk[k] = dv[k] >> NB_SHIFT;
            rk[k] = atomicAdd(&cnt[bk[k]], 1);
        }
    } else {
#pragma unroll
        for (int k = 0; k < 8; ++k) {
            if (e0 + k < E) {
                dv[k] = dst[e0 + k];
                sv[k] = src[e0 + k];
                ev[k] = ef[e0 + k];
                bk[k] = dv[k] >> NB_SHIFT;
                rk[k] = atomicAdd(&cnt[bk[k]], 1);
            } else {
                bk[k] = -1;
            }
        }
    }
    __syncthreads();

    // exclusive scan of cnt[0..MAXNB-1], 4/thread: wave shfl scan + cross-wave
    int c0 = cnt[4 * t], c1 = cnt[4 * t + 1], c2 = cnt[4 * t + 2], c3 = cnt[4 * t + 3];
    int ts = c0 + c1 + c2 + c3;
    int incl = ts;
#pragma unroll
    for (int o = 1; o < 64; o <<= 1) {
        int u = __shfl_up(incl, o);
        if (lane >= o) incl += u;
    }
    if (lane == 63) wsum[wv] = incl;
    __syncthreads();
    if (t < 8) {
        int v = wsum[t];
        int inc = v;
#pragma unroll
        for (int o = 1; o < 8; o <<= 1) {
            int u = __shfl_up(inc, o);
            if (t >= o) inc += u;
        }
        wbase[t] = inc - v;
    }
    __syncthreads();
    int ex = wbase[wv] + (incl - ts);
    lbase[4 * t]     = ex;
    lbase[4 * t + 1] = ex + c0;
    lbase[4 * t + 2] = ex + c0 + c1;
    lbase[4 * t + 3] = ex + c0 + c1 + c2;
    __syncthreads();

    // stage ranked payloads
#pragma unroll
    for (int k = 0; k < 8; ++k) {
        if (bk[k] >= 0) {
            int pos = lbase[bk[k]] + rk[k];
            stage[pos] = make_int2(((dv[k] & (BNODES - 1)) << SRC_BITS) | sv[k],
                                   __float_as_int(ev[k]));
            sbuck[pos] = (unsigned short)bk[k];
        }
    }
    // global reserve per bucket; cnt[b] becomes (global_base - local_base)
    for (int i = t; i < MAXNB; i += BIN_T) {
        int c = cnt[i];
        cnt[i] = (c ? atomicAdd(&gcur[i], c) : 0) - lbase[i];
    }
    __syncthreads();

    // coalesced flush: consecutive stage entries -> consecutive global addrs
    int s_total = min(BIN_S, E - blockIdx.x * BIN_S);
    for (int i = t; i < s_total; i += BIN_T) {
        int b = sbuck[i];
        gpay[cnt[b] + i] = stage[i];
    }
}

// Fused bucket sort + gather. One block per 64-node bucket, 8 waves.
// LDS counting-sort of the bucket's keys (esum accumulated at load time),
// then wave w gathers node-slots r = i*8+w with the r10-proven 8-deep
// register loop, writing each output row once. Multi-chunk buckets
// (>SGCAP edges) accumulate partial rows in an LDS tile.
__global__ __launch_bounds__(GAT_T) void bgather_kernel(const __half* __restrict__ hg,
                                                        const int2* __restrict__ gpay,
                                                        const int* __restrict__ goff,
                                                        float* __restrict__ out,
                                                        int N) {
    __shared__ int   cnt[BNODES];
    __shared__ int   lb[BNODES];
    __shared__ float esum[BNODES];
    __shared__ int   skey[SGCAP];            // 8 KB
    __shared__ float tile[BNODES * 64];      // 16 KB (multi-chunk only)

    const int t    = threadIdx.x;
    const int b    = blockIdx.x;
    const int wave = t >> 6;
    const int lane = t & 63;
    const int lo   = goff[b];
    const int hi   = goff[b + 1];
    const bool multi = (hi - lo) > SGCAP;

    if (t < BNODES) esum[t] = 0.f;
    if (multi)
        for (int i = t; i < BNODES * 64; i += GAT_T) tile[i] = 0.f;

    for (int cbase = lo; cbase < hi; cbase += SGCAP) {
        const int csize = min(SGCAP, hi - cbase);

        __syncthreads();               // esum/tile init & prev-chunk reads done
        if (t < BNODES) cnt[t] = 0;
        __syncthreads();

        // load + rank (4 payloads/thread, coalesced); esum at load time
        int kv[4]; int rk[4]; int dr[4];
#pragma unroll
        for (int k = 0; k < 4; ++k) {
            int idx = t + k * GAT_T;
            dr[k] = -1;
            if (idx < csize) {
                int2 p = gpay[cbase + idx];
                kv[k] = p.x;
                dr[k] = p.x >> SRC_BITS;
                rk[k] = atomicAdd(&cnt[dr[k]], 1);
                atomicAdd(&esum[dr[k]], __int_as_float(p.y));
            }
        }
        __syncthreads();

        // wave-0 shfl exclusive scan of the 64 counters
        if (t < 64) {
            int v = cnt[t];
            int inc = v;
#pragma unroll
            for (int o = 1; o < 64; o <<= 1) {
                int u = __shfl_up(inc, o);
                if (t >= o) inc += u;
            }
            lb[t] = inc - v;
        }
        __syncthreads();

        // place sorted keys
#pragma unroll
        for (int k = 0; k < 4; ++k)
            if (dr[k] >= 0) skey[lb[dr[k]] + rk[k]] = kv[k];
        __syncthreads();

        // gather: wave handles slots r = i*8 + wave, one at a time
#pragma unroll
        for (int i = 0; i < 8; ++i) {
            const int r  = i * 8 + wave;
            const int s0 = lb[r];
            const int c  = cnt[r];
            float a0 = 0.f, a1 = 0.f, a2 = 0.f, a3 = 0.f;
            float a4 = 0.f, a5 = 0.f, a6 = 0.f, a7 = 0.f;
            int j = 0;
            for (; j + 7 < c; j += 8) {
                int s_0 = skey[s0 + j]     & SRC_MASK;
                int s_1 = skey[s0 + j + 1] & SRC_MASK;
                int s_2 = skey[s0 + j + 2] & SRC_MASK;
                int s_3 = skey[s0 + j + 3] & SRC_MASK;
                int s_4 = skey[s0 + j + 4] & SRC_MASK;
                int s_5 = skey[s0 + j + 5] & SRC_MASK;
                int s_6 = skey[s0 + j + 6] & SRC_MASK;
                int s_7 = skey[s0 + j + 7] & SRC_MASK;
                a0 += __half2float(hg[(size_t)s_0 * 64 + lane]);
                a1 += __half2float(hg[(size_t)s_1 * 64 + lane]);
                a2 += __half2float(hg[(size_t)s_2 * 64 + lane]);
                a3 += __half2float(hg[(size_t)s_3 * 64 + lane]);
                a4 += __half2float(hg[(size_t)s_4 * 64 + lane]);
                a5 += __half2float(hg[(size_t)s_5 * 64 + lane]);
                a6 += __half2float(hg[(size_t)s_6 * 64 + lane]);
                a7 += __half2float(hg[(size_t)s_7 * 64 + lane]);
            }
            for (; j + 3 < c; j += 4) {
                int s_0 = skey[s0 + j]     & SRC_MASK;
                int s_1 = skey[s0 + j + 1] & SRC_MASK;
                int s_2 = skey[s0 + j + 2] & SRC_MASK;
                int s_3 = skey[s0 + j + 3] & SRC_MASK;
                a0 += __half2float(hg[(size_t)s_0 * 64 + lane]);
                a1 += __half2float(hg[(size_t)s_1 * 64 + lane]);
                a2 += __half2float(hg[(size_t)s_2 * 64 + lane]);
                a3 += __half2float(hg[(size_t)s_3 * 64 + lane]);
            }
            for (; j < c; ++j) {
                a0 += __half2float(hg[(size_t)(skey[s0 + j] & SRC_MASK) * 64 + lane]);
            }
            float sum = ((a0 + a1) + (a2 + a3)) + ((a4 + a5) + (a6 + a7));
            if (!multi) {
                int node = b * BNODES + r;
                if (node < N) out[(size_t)node * 65 + lane] = sum;
            } else {
                tile[r * 64 + lane] += sum;
            }
        }
    }

    __syncthreads();
    if (multi) {
#pragma unroll
        for (int i = 0; i < 8; ++i) {
            int r = i * 8 + wave;
            int node = b * BNODES + r;
            if (node < N) out[(size_t)node * 65 + lane] = tile[r * 64 + lane];
        }
    }
    // efeat column
    if (t < BNODES) {
        int node = b * BNODES + t;
        if (node < N) out[(size_t)node * 65 + 64] = esum[t];
    }
}

// ---------------------- fallback (always correct) --------------------------

__global__ void atomic_fallback_kernel(const float* __restrict__ gemb,
                                       const float* __restrict__ efeat,
                                       const int* __restrict__ src,
                                       const int* __restrict__ dst,
                                       float* __restrict__ out, int E) {
    int eidx = blockIdx.x * 4 + (threadIdx.x >> 6);
    int lane = threadIdx.x & 63;
    if (eidx >= E) return;
    int s = src[eidx];
    int d = dst[eidx];
    float v = gemb[(size_t)s * 64 + lane];
    atomicAdd(&out[(size_t)d * 65 + lane], v);
    if (lane == 0) atomicAdd(&out[(size_t)d * 65 + 64], efeat[eidx]);
}

// ---------------------------------------------------------------------------

extern "C" void kernel_launch(void* const* d_in, const int* in_sizes, int n_in,
                              void* d_out, int out_size, void* d_ws, size_t ws_size,
                              hipStream_t stream) {
    const float* gemb  = (const float*)d_in[0];   // [N, 64]
    const float* efeat = (const float*)d_in[1];   // [E]
    const int*   src   = (const int*)d_in[2];     // [E]
    const int*   dst   = (const int*)d_in[3];     // [E]
    float*       out   = (float*)d_out;           // [N, 65]

    const int N  = in_sizes[0] / 64;
    const int E  = in_sizes[1];
    const int NB = (N + BNODES - 1) >> NB_SHIFT;

    auto aln = [](size_t x) { return (x + 63) & ~(size_t)63; };
    size_t off_counts = 0;                                    // [MAXNB]
    size_t off_goff   = off_counts + (size_t)MAXNB * 4;
    size_t off_gcur   = aln(off_goff + (size_t)(NB + 1) * 4);
    size_t off_gpay   = aln(off_gcur + (size_t)NB * 4);
    size_t off_hg     = aln(off_gpay + (size_t)E * 8);
    size_t needed     = off_hg + (size_t)N * 64 * 2;

    if (N > (1 << SRC_BITS) || NB > MAXNB || ws_size < needed) {
        hipMemsetAsync(d_out, 0, (size_t)out_size * sizeof(float), stream);
        int blocks = (E + 3) / 4;
        atomic_fallback_kernel<<<blocks, 256, 0, stream>>>(gemb, efeat, src, dst, out, E);
        return;
    }

    char*   ws     = (char*)d_ws;
    int*    counts = (int*)(ws + off_counts);
    int*    goff   = (int*)(ws + off_goff);
    int*    gcur   = (int*)(ws + off_gcur);
    int2*   gpay   = (int2*)(ws + off_gpay);
    __half* hg     = (__half*)(ws + off_hg);

    hipMemsetAsync(counts, 0, (size_t)MAXNB * 4, stream);

    int n_emb    = N * 64;
    int c_blocks = (n_emb + BIN_T * 8 - 1) / (BIN_T * 8);
    int h_blocks = (E + BIN_S - 1) / BIN_S;
    convhist_kernel<<<c_blocks + h_blocks, BIN_T, 0, stream>>>(
        gemb, hg, n_emb, c_blocks, dst, counts, E, NB);

    scan_kernel<<<1, 1024, 0, stream>>>(counts, goff, gcur, NB);
    bin_kernel<<<h_blocks, BIN_T, 0, stream>>>(src, efeat, dst, gcur, gpay, E);
    bgather_kernel<<<NB, GAT_T, 0, stream>>>(hg, gpay, goff, out, N);
}